// Round 17
// baseline (432.650 us; speedup 1.0000x reference)
//
#include <hip/hip_runtime.h>
#include <math.h>

typedef unsigned short u16;
typedef __bf16 bf16x8 __attribute__((ext_vector_type(8)));
typedef float f32x4 __attribute__((ext_vector_type(4)));

typedef __attribute__((address_space(1))) const void gas_t;
typedef __attribute__((address_space(3))) void las_t;

__device__ __forceinline__ void async16(const void* g, void* l) {
    __builtin_amdgcn_global_load_lds((gas_t*)g, (las_t*)l, 16, 0, 0);
}

__device__ __forceinline__ float b2f(u16 u) {
    union { unsigned u; float f; } c; c.u = ((unsigned)u) << 16; return c.f;
}
__device__ __forceinline__ u16 f2b(float f) {
    union { float f; unsigned u; } c; c.f = f;
    unsigned x = c.u + 0x7FFFu + ((c.u >> 16) & 1u);
    return (u16)(x >> 16);
}

// ---------------- f32 -> bf16 conversion ----------------
__global__ __launch_bounds__(256)
void cvt_kernel(const float* __restrict__ in, u16* __restrict__ out, int n4) {
    int i = blockIdx.x * 256 + threadIdx.x;
    int stride = gridDim.x * 256;
    for (; i < n4; i += stride) {
        float4 f = ((const float4*)in)[i];
        ushort4 u;
        u.x = f2b(f.x); u.y = f2b(f.y); u.z = f2b(f.z); u.w = f2b(f.w);
        ((ushort4*)out)[i] = u;
    }
}

// ---------------- 4-source f32 -> bf16 into contiguous wcat|ow (q|k|v|o) -----------
__global__ __launch_bounds__(256)
void cvt4_kernel(const float* __restrict__ a, const float* __restrict__ b,
                 const float* __restrict__ c, const float* __restrict__ d,
                 u16* __restrict__ out) {
    int i = blockIdx.x * 256 + threadIdx.x;        // 0..2097151 quads
    int seg = i >> 19, off = i & 524287;           // 524288 quads per 2M-elem weight
    const float* src = (seg == 0) ? a : (seg == 1) ? b : (seg == 2) ? c : d;
    float4 f = ((const float4*)src)[off];
    ushort4 u;
    u.x = f2b(f.x); u.y = f2b(f.y); u.z = f2b(f.z); u.w = f2b(f.w);
    ((ushort4*)out)[i] = u;
}

// ---------------- rotated phase-weights: wp[bh][p*64+v][d] ----------------
// Fold RoPE into W (adjoint of rotate_half):
//   Wp[v,d] = cos_p[d]*W[v,d] + sin_p[d]*( d<32 ? +W[v,d+32] : -W[v,d-32] )
__global__ __launch_bounds__(256)
void wprep_kernel(const float* __restrict__ W, u16* __restrict__ wp) {
    int idx = blockIdx.x * 256 + threadIdx.x;   // < 64*6*64*64 = 1572864
    int d = idx & 63;
    int v = (idx >> 6) & 63;
    int p = (idx >> 12) % 6;
    int bh = idx / 24576;
    const float* Wb = W + (((size_t)bh * 64 + v) << 6);
    float invf = expf(-(float)(d & 31) * (9.210340371976184f / 32.f)); // 10000^(-(d%32)/32)
    float ang = (float)p * invf;
    float c = cosf(ang), s = sinf(ang);
    float rot = (d < 32) ? Wb[d + 32] : -Wb[d - 32];
    wp[idx] = f2b(c * Wb[d] + s * rot);
}

// ---------------- 256^2-tile bf16 GEMM, fine-grained 4-phase pipeline (R13 core)
// C = A @ Bw^T. A: MxK, Bw: NxK, row-major bf16. 512 threads = 8 waves (2Mx4N).
// LDS 128 KiB = 2 buf x { A[k0|k1] , B[k0|k1] } x 256 rows x 32 elems (64B rows).
// Per K-tile: 4 phases along (k-half, m-half); each phase: {stage 2 loads of
// NEXT tile's half || 4-8 ds_read_b128 of THIS phase's frags || 16 MFMA}.
// Waits: P0/P2 vmcnt(4) (counted, partial); vmcnt(0) only at the last tile.
// HW-verified R13/R15: 986 TF, MfmaUtil 44.3%, 0 conflicts, reproducible.
// MODE 0 additionally runs the m201-style LOCKSTEP: one s_barrier after each
// phase's MFMA cluster (added barrier cannot create races -- only restricts
// interleavings; counts uniform). A/B vs R15's qkv isolates this element.
// MODE 1 epilogue uses NON-TEMPORAL resid load / out store (f32x4 clang
// vector type -- float4/HIP_vector_type is rejected by the builtin): the
// 268 MB single-use f32 streams stop evicting A/B panels from L2/L3.
// MODE 0: write bf16 C.  MODE 1: out_f32 = resid + sigmoid(*scale)*C (N=2048).
template<int MODE>
__global__ __launch_bounds__(512, 2)
void gemm_8ph(const u16* __restrict__ A, const u16* __restrict__ Bw,
              int M, int N, int K,
              u16* __restrict__ obf, const float* __restrict__ resid,
              float* __restrict__ of32, const float* __restrict__ scale_ptr) {
    __shared__ __align__(16) char lsb[2][65536];  // per buf: A-k0|A-k1|B-k0|B-k1 (16KB each)
    const int tid = threadIdx.x;
    const int lane = tid & 63;
    const int wm = (tid >> 6) >> 2;   // 0..1
    const int wn = (tid >> 6) & 3;    // 0..3
    const int r15 = lane & 15;
    const int nbx = N >> 8;

    int m0, n0;
    if (MODE == 1) {
        // m-grouped XCD swizzle (requires nbx == 8): XCD x -> m in [x*8, x*8+8)
        int x = blockIdx.x & 7, idx = blockIdx.x >> 3;
        int ml = idx >> 3, n = idx & 7;
        m0 = (x * 8 + ml) << 8;
        n0 = n << 8;
    } else {
        int bid = blockIdx.x;
        const int cpx = gridDim.x >> 3;
        bid = (bid & 7) * cpx + (bid >> 3);
        m0 = (bid / nbx) << 8;
        n0 = (bid % nbx) << 8;
    }

    f32x4 acc[8][4];
#pragma unroll
    for (int i = 0; i < 8; ++i)
#pragma unroll
        for (int j = 0; j < 4; ++j) acc[i][j] = (f32x4){0.f, 0.f, 0.f, 0.f};

    const char* Ab = (const char*)A;
    const char* Bb = (const char*)Bw;
    const int ssl = (((tid & 3) ^ ((tid >> 3) & 3)) << 4);        // staging src slot
    const int slotRd = ((((lane >> 4) ^ ((r15 >> 1) & 3))) << 4); // read slot
    const int nkt = K >> 6;

    // stage one 16KB half: matrix mat (0=A,1=B), k-half kh, of tile kt -> buf
    auto stage_half = [&](int buf, int mat, int kh, int kt) {
        const char* src = mat ? Bb : Ab;
        const int b0 = mat ? n0 : m0;
        char* dst = &lsb[buf][0] + mat * 32768 + kh * 16384;
        const int k0 = kt * 64 + kh * 32;
#pragma unroll
        for (int i = 0; i < 2; ++i) {
            int row = i * 128 + (tid >> 2);
            async16(src + ((size_t)(b0 + row) * K + k0) * 2 + ssl,
                    dst + i * 8192 + tid * 16);
        }
    };

    // prologue: tile 0, all 4 halves in canonical queue order
    stage_half(0, 0, 0, 0);
    stage_half(0, 1, 0, 0);
    stage_half(0, 0, 1, 0);
    stage_half(0, 1, 1, 0);

    for (int kt = 0; kt < nkt; ++kt) {
        const int cur = kt & 1;
        const char* base = &lsb[cur][0];
#pragma unroll
        for (int kh = 0; kh < 2; ++kh) {
            // ---- phase 2*kh: k-half publish + m-low quadrant ----
            if (kt < nkt - 1) asm volatile("s_waitcnt vmcnt(4)" ::: "memory");
            else if (kh == 0) asm volatile("s_waitcnt vmcnt(0)" ::: "memory");
            __builtin_amdgcn_s_barrier();
            if (kt + 1 < nkt) stage_half(cur ^ 1, 0, kh, kt + 1);   // A-kh of next

            const char* Ak = base + kh * 16384;
            const char* Bk = base + 32768 + kh * 16384;
            bf16x8 bf[4], afl[4];
#pragma unroll
            for (int n = 0; n < 4; ++n) {
                int row = wn * 64 + n * 16 + r15;
                bf[n] = *(const bf16x8*)(Bk + row * 64 + slotRd);
            }
#pragma unroll
            for (int m = 0; m < 4; ++m) {
                int row = wm * 128 + m * 16 + r15;
                afl[m] = *(const bf16x8*)(Ak + row * 64 + slotRd);
            }
            __builtin_amdgcn_s_setprio(1);
#pragma unroll
            for (int m = 0; m < 4; ++m)
#pragma unroll
                for (int n = 0; n < 4; ++n)
                    acc[m][n] = __builtin_amdgcn_mfma_f32_16x16x32_bf16(bf[n], afl[m], acc[m][n], 0, 0, 0);
            __builtin_amdgcn_s_setprio(0);
            if (MODE == 0) __builtin_amdgcn_s_barrier();   // lockstep phase end

            // ---- phase 2*kh+1: m-high quadrant ----
            if (kt + 1 < nkt) stage_half(cur ^ 1, 1, kh, kt + 1);   // B-kh of next
            bf16x8 afh[4];
#pragma unroll
            for (int m = 0; m < 4; ++m) {
                int row = wm * 128 + 64 + m * 16 + r15;
                afh[m] = *(const bf16x8*)(Ak + row * 64 + slotRd);
            }
            __builtin_amdgcn_s_setprio(1);
#pragma unroll
            for (int m = 0; m < 4; ++m)
#pragma unroll
                for (int n = 0; n < 4; ++n)
                    acc[4 + m][n] = __builtin_amdgcn_mfma_f32_16x16x32_bf16(bf[n], afh[m], acc[4 + m][n], 0, 0, 0);
            __builtin_amdgcn_s_setprio(0);
            if (MODE == 0) __builtin_amdgcn_s_barrier();   // lockstep phase end
        }
    }

    float sig = 0.f;
    if (MODE == 1) sig = 1.f / (1.f + expf(-scale_ptr[0]));

    // Swapped C/D layout: M-row = lane&15 (+m*16), N-col = (lane>>4)*4 + r (+n*16)
    const int crow = wm * 128 + r15;
    const int ccol0 = wn * 64 + ((lane >> 4) << 2);
#pragma unroll
    for (int m = 0; m < 8; ++m) {
#pragma unroll
        for (int n = 0; n < 4; ++n) {
            size_t gi = (size_t)(m0 + crow + m * 16) * N + (n0 + ccol0 + n * 16);
            if (MODE == 0) {
                ushort4 u;
                u.x = f2b(acc[m][n][0]); u.y = f2b(acc[m][n][1]);
                u.z = f2b(acc[m][n][2]); u.w = f2b(acc[m][n][3]);
                *(ushort4*)&obf[gi] = u;
            } else {
                f32x4 rv = __builtin_nontemporal_load((const f32x4*)&resid[gi]);
                f32x4 o = rv + sig * acc[m][n];
                __builtin_nontemporal_store(o, (f32x4*)&of32[gi]);
            }
        }
    }
}

// ---------------- fused phase-reads + softmax + merged (q from qkv, stride 3072) ----
__global__ __launch_bounds__(256)
void reads_kernel(const u16* __restrict__ qkv, const u16* __restrict__ wp,
                  u16* __restrict__ merged) {
    __shared__ __align__(16) u16 lsW[384 * 64];   // swizzled
    const int tid = threadIdx.x, lane = tid & 63, w = tid >> 6;
    const int bh = blockIdx.x, tc = blockIdx.y;
    const int b = bh >> 4, h = bh & 15;

    const char* src = (const char*)(wp + (size_t)bh * 24576);
#pragma unroll
    for (int it = 0; it < 12; ++it) {
        int x = (it * 256 + tid) << 4;            // dest byte in LDS (linear)
        int row = x >> 7;
        int wb = x & 127;
        *(uint4*)((char*)lsW + x) = *(const uint4*)(src + row * 128 + (wb ^ ((row & 7) << 4)));
    }
    __syncthreads();

    for (int tt = 0; tt < 4; ++tt) {
        const int t0 = tc * 256 + tt * 64 + w * 16;
        const size_t qoff = ((size_t)b * 4096 + t0 + (lane & 15)) * 3072 + h * 64 + ((lane >> 4) << 3);
        uint4 a0u = *(const uint4*)&qkv[qoff];
        uint4 a1u = *(const uint4*)&qkv[qoff + 32];

        float ss = 0.f;
        {
            unsigned a[8] = {a0u.x, a0u.y, a0u.z, a0u.w, a1u.x, a1u.y, a1u.z, a1u.w};
#pragma unroll
            for (int i = 0; i < 8; ++i) {
                union { unsigned u; float f; } lo, hi;
                lo.u = a[i] << 16; hi.u = a[i] & 0xFFFF0000u;
                ss += lo.f * lo.f + hi.f * hi.f;
            }
        }
        ss += __shfl_xor(ss, 16);
        ss += __shfl_xor(ss, 32);
        float sc = 1.0f / fmaxf(sqrtf(ss), 1e-12f);   // lane-local: this lane's t-row

        bf16x8 a0 = __builtin_bit_cast(bf16x8, a0u);
        bf16x8 a1 = __builtin_bit_cast(bf16x8, a1u);

        f32x4 acc[24];
#pragma unroll
        for (int i = 0; i < 24; ++i) acc[i] = (f32x4){0.f, 0.f, 0.f, 0.f};
#pragma unroll
        for (int kk = 0; kk < 2; ++kk) {
            bf16x8 a = kk ? a1 : a0;
            const int kb = kk * 64 + ((lane >> 4) << 4);
#pragma unroll
            for (int nf = 0; nf < 24; ++nf) {
                int row = nf * 16 + (lane & 15);
                bf16x8 bb = *(const bf16x8*)((const char*)lsW + row * 128 + (kb ^ ((row & 7) << 4)));
                acc[nf] = __builtin_amdgcn_mfma_f32_16x16x32_bf16(bb, a, acc[nf], 0, 0, 0);
            }
        }

        // scores -> softmax over 6 phases (scalar per lane; lane owns t-row = lane&15)
        float alpha[6];
#pragma unroll
        for (int p = 0; p < 6; ++p) {
            float x = 0.f;
#pragma unroll
            for (int fv = 0; fv < 4; ++fv) {
                f32x4 v = acc[p * 4 + fv];
#pragma unroll
                for (int r = 0; r < 4; ++r) x += v[r] * v[r];
            }
            x += __shfl_xor(x, 16);
            x += __shfl_xor(x, 32);
            alpha[p] = sqrtf(x) * sc * (5.0f / 8.0f);  // TEMP/sqrt(DV)
        }
        {
            float m = alpha[0];
#pragma unroll
            for (int p = 1; p < 6; ++p) m = fmaxf(m, alpha[p]);
            float s = 0.f;
#pragma unroll
            for (int p = 0; p < 6; ++p) { float e = expf(alpha[p] - m); s += e; alpha[p] = e; }
            float inv = 1.f / s;
#pragma unroll
            for (int p = 0; p < 6; ++p) alpha[p] *= inv;
        }
#pragma unroll
        for (int fv = 0; fv < 4; ++fv) {
            float o[4];
#pragma unroll
            for (int r = 0; r < 4; ++r) {
                float acc_o = 0.f;
#pragma unroll
                for (int p = 0; p < 6; ++p) acc_o += alpha[p] * acc[p * 4 + fv][r];
                o[r] = acc_o * sc;
            }
            size_t gi = ((size_t)b * 4096 + t0 + (lane & 15)) * 1024
                        + h * 64 + fv * 16 + ((lane >> 4) << 2);
            ushort4 u;
            u.x = f2b(o[0]); u.y = f2b(o[1]); u.z = f2b(o[2]); u.w = f2b(o[3]);
            *(ushort4*)&merged[gi] = u;
        }
    }
}

// ---------------- MFMA residual: part[sp][bh][v][d] = sum_t v[t,v]*kn[t,d] -----------
// (HW-verified R11: passed) Fused k-norm; per 32-t chunk: coalesced k/v reads
// -> octet shfl norm -> swizzled transpose-write -> K=32 MFMA.
__global__ __launch_bounds__(256)
void resid_mfma(const u16* __restrict__ qkv, float* __restrict__ part) {
    __shared__ __align__(16) u16 kT[64 * 32];
    __shared__ __align__(16) u16 vT[64 * 32];
    const int bh = blockIdx.x, sp = blockIdx.y;
    const int b = bh >> 4, h = bh & 15;
    const int tid = threadIdx.x, lane = tid & 63, wv = tid >> 6;
    const int tl = tid >> 3;   // 0..31: t within chunk
    const int c8 = tid & 7;    // d-octet

    f32x4 acc[4];
#pragma unroll
    for (int dt = 0; dt < 4; ++dt) acc[dt] = (f32x4){0.f, 0.f, 0.f, 0.f};

    const int r15 = lane & 15, g = lane >> 4;
    const int vrow = wv * 16 + r15;
    const int vaddr = vrow * 64 + ((g ^ ((vrow >> 3) & 3)) << 4);
    int kaddr[4];
#pragma unroll
    for (int dt = 0; dt < 4; ++dt) {
        int kr = dt * 16 + r15;
        kaddr[dt] = kr * 64 + ((g ^ ((kr >> 3) & 3)) << 4);
    }

    for (int c = 0; c < 8; ++c) {
        size_t row = ((size_t)b * 4096 + sp * 256 + c * 32 + tl) * 3072 + h * 64 + c8 * 8;
        uint4 kq = *(const uint4*)&qkv[row + 1024];
        uint4 vq = *(const uint4*)&qkv[row + 2048];

        unsigned kw[4] = {kq.x, kq.y, kq.z, kq.w};
        unsigned vw[4] = {vq.x, vq.y, vq.z, vq.w};
        float kf[8];
        float ss = 0.f;
#pragma unroll
        for (int i = 0; i < 4; ++i) {
            union { unsigned u; float f; } lo, hi;
            lo.u = kw[i] << 16; hi.u = kw[i] & 0xFFFF0000u;
            kf[2 * i] = lo.f; kf[2 * i + 1] = hi.f;
            ss += lo.f * lo.f + hi.f * hi.f;
        }
        ss += __shfl_xor(ss, 1);
        ss += __shfl_xor(ss, 2);
        ss += __shfl_xor(ss, 4);
        float sc = 1.0f / fmaxf(sqrtf(ss), 1e-12f);

        const int gt = (tl >> 3), o = (tl & 7);
#pragma unroll
        for (int j = 0; j < 8; ++j) {
            int r = 8 * c8 + j;
            int a = r * 32 + ((gt ^ ((r >> 3) & 3)) * 8 + o);
            kT[a] = f2b(kf[j] * sc);
            vT[a] = (u16)((vw[j >> 1] >> ((j & 1) * 16)) & 0xFFFFu);
        }
        __syncthreads();

        bf16x8 vf = *(const bf16x8*)((const char*)vT + vaddr);
#pragma unroll
        for (int dt = 0; dt < 4; ++dt) {
            bf16x8 knf = *(const bf16x8*)((const char*)kT + kaddr[dt]);
            acc[dt] = __builtin_amdgcn_mfma_f32_16x16x32_bf16(knf, vf, acc[dt], 0, 0, 0);
        }
        __syncthreads();
    }

    float* dst = part + ((size_t)sp * 64 + bh) * 4096 + (size_t)vrow * 64;
#pragma unroll
    for (int dt = 0; dt < 4; ++dt) {
        float4 f4;
        f4.x = acc[dt][0]; f4.y = acc[dt][1]; f4.z = acc[dt][2]; f4.w = acc[dt][3];
        *(float4*)(dst + dt * 16 + g * 4) = f4;
    }
}

// ---------------- W_new = 0.9*aged + sum(part)/T ----------------
__global__ __launch_bounds__(256)
void wnew_kernel(const float* __restrict__ W, const float* __restrict__ part,
                 float* __restrict__ outW) {
    int idx = blockIdx.x * 256 + threadIdx.x;   // 262144
    int d = idx & 63;
    float w = W[idx];
    float rot = (d < 32) ? -W[idx + 32] : W[idx - 32];
    float invf = expf(-(float)(d & 31) * (9.210340371976184f / 32.f));
    float aged = w * cosf(invf) + rot * sinf(invf);
    float r = 0.f;
#pragma unroll
    for (int s = 0; s < 16; ++s) r += part[(size_t)s * 262144 + idx];
    outW[idx] = 0.9f * aged + r * (1.0f / 4096.0f);
}

extern "C" void kernel_launch(void* const* d_in, const int* in_sizes, int n_in,
                              void* d_out, int out_size, void* d_ws, size_t ws_size,
                              hipStream_t stream) {
    const float* hidden = (const float*)d_in[0];
    const float* Wturn  = (const float*)d_in[1];
    const float* qw     = (const float*)d_in[2];
    const float* ow     = (const float*)d_in[3];
    const float* kw     = (const float*)d_in[4];
    const float* vw     = (const float*)d_in[5];
    const float* rs     = (const float*)d_in[6];
    float* out  = (float*)d_out;
    float* outW = out + 33554432;

    char* ws = (char*)d_ws;
    u16* hid_bf = (u16*)(ws + 0);             // 16384x2048 bf16 (67,108,864 B)
    u16* qkv    = (u16*)(ws + 67108864);      // 16384x3072 bf16 (100,663,296 B)
    u16* mrg    = (u16*)(ws + 167772160);     // 16384x1024 bf16 (33,554,432 B)
    u16* wcat   = (u16*)(ws + 201326592);     // 3072x2048 bf16 (12,582,912 B): q|k|v
    u16* ow_bf  = (u16*)(ws + 213909504);     // 2048x1024 bf16 (4,194,304 B) -- contiguous after wcat
    u16* wp     = (u16*)(ws + 218103808);     // 64x384x64 bf16 (3,145,728 B)
    float* part = (float*)(ws + 222298112);   // 16x262144 f32 (end ~239 MB)

    cvt_kernel<<<4096, 256, 0, stream>>>(hidden, hid_bf, 33554432 / 4);
    cvt4_kernel<<<8192, 256, 0, stream>>>(qw, kw, vw, ow, wcat);   // wcat|ow_bf contiguous
    wprep_kernel<<<6144, 256, 0, stream>>>(Wturn, wp);

    // fused q|k|v projection: (16384x2048) @ (3072x2048)^T -> qkv
    gemm_8ph<0><<<768, 512, 0, stream>>>(hid_bf, wcat, 16384, 3072, 2048, qkv, nullptr, nullptr, nullptr);

    reads_kernel<<<dim3(64, 16), 256, 0, stream>>>(qkv, wp, mrg);
    gemm_8ph<1><<<512, 512, 0, stream>>>(mrg, ow_bf, 16384, 2048, 1024, nullptr, hidden, out, rs);
    resid_mfma<<<dim3(64, 16), 256, 0, stream>>>(qkv, part);
    wnew_kernel<<<1024, 256, 0, stream>>>(Wturn, part, outW);
}

// Round 18
// 428.549 us; speedup vs baseline: 1.0096x; 1.0096x over previous
//
#include <hip/hip_runtime.h>
#include <math.h>

typedef unsigned short u16;
typedef __bf16 bf16x8 __attribute__((ext_vector_type(8)));
typedef float f32x4 __attribute__((ext_vector_type(4)));

typedef __attribute__((address_space(1))) const void gas_t;
typedef __attribute__((address_space(3))) void las_t;

__device__ __forceinline__ void async16(const void* g, void* l) {
    __builtin_amdgcn_global_load_lds((gas_t*)g, (las_t*)l, 16, 0, 0);
}

__device__ __forceinline__ float b2f(u16 u) {
    union { unsigned u; float f; } c; c.u = ((unsigned)u) << 16; return c.f;
}
__device__ __forceinline__ u16 f2b(float f) {
    union { float f; unsigned u; } c; c.f = f;
    unsigned x = c.u + 0x7FFFu + ((c.u >> 16) & 1u);
    return (u16)(x >> 16);
}

// ---------------- f32 -> bf16 conversion ----------------
__global__ __launch_bounds__(256)
void cvt_kernel(const float* __restrict__ in, u16* __restrict__ out, int n4) {
    int i = blockIdx.x * 256 + threadIdx.x;
    int stride = gridDim.x * 256;
    for (; i < n4; i += stride) {
        float4 f = ((const float4*)in)[i];
        ushort4 u;
        u.x = f2b(f.x); u.y = f2b(f.y); u.z = f2b(f.z); u.w = f2b(f.w);
        ((ushort4*)out)[i] = u;
    }
}

// ---------------- 4-source f32 -> bf16 into contiguous wcat|ow (q|k|v|o) -----------
__global__ __launch_bounds__(256)
void cvt4_kernel(const float* __restrict__ a, const float* __restrict__ b,
                 const float* __restrict__ c, const float* __restrict__ d,
                 u16* __restrict__ out) {
    int i = blockIdx.x * 256 + threadIdx.x;        // 0..2097151 quads
    int seg = i >> 19, off = i & 524287;           // 524288 quads per 2M-elem weight
    const float* src = (seg == 0) ? a : (seg == 1) ? b : (seg == 2) ? c : d;
    float4 f = ((const float4*)src)[off];
    ushort4 u;
    u.x = f2b(f.x); u.y = f2b(f.y); u.z = f2b(f.z); u.w = f2b(f.w);
    ((ushort4*)out)[i] = u;
}

// ---------------- rotated phase-weights: wp[bh][p*64+v][d] ----------------
// Fold RoPE into W (adjoint of rotate_half):
//   Wp[v,d] = cos_p[d]*W[v,d] + sin_p[d]*( d<32 ? +W[v,d+32] : -W[v,d-32] )
__global__ __launch_bounds__(256)
void wprep_kernel(const float* __restrict__ W, u16* __restrict__ wp) {
    int idx = blockIdx.x * 256 + threadIdx.x;   // < 64*6*64*64 = 1572864
    int d = idx & 63;
    int v = (idx >> 6) & 63;
    int p = (idx >> 12) % 6;
    int bh = idx / 24576;
    const float* Wb = W + (((size_t)bh * 64 + v) << 6);
    float invf = expf(-(float)(d & 31) * (9.210340371976184f / 32.f)); // 10000^(-(d%32)/32)
    float ang = (float)p * invf;
    float c = cosf(ang), s = sinf(ang);
    float rot = (d < 32) ? Wb[d + 32] : -Wb[d - 32];
    wp[idx] = f2b(c * Wb[d] + s * rot);
}

// ---------------- 256^2-tile bf16 GEMM, fine-grained 4-phase pipeline (R13-exact)
// C = A @ Bw^T. A: MxK, Bw: NxK, row-major bf16. 512 threads = 8 waves (2Mx4N).
// LDS 128 KiB = 2 buf x { A[k0|k1] , B[k0|k1] } x 256 rows x 32 elems (64B rows).
// Per K-tile: 4 phases along (k-half, m-half); each phase: {stage 2 loads of
// NEXT tile's half || 4-8 ds_read_b128 of THIS phase's frags || 16 MFMA}.
// Waits: P0/P2 vmcnt(4) (counted, partial); vmcnt(0) only at the last tile.
// HW-verified R13/R15: 986 TF, MfmaUtil 44.3%, 0 conflicts, reproducible.
// SCHEDULE IS SETTLED -- A/B history: coarse ring (R12: +3%), 1-barrier/tile
// (R14: -6%), lockstep phase barriers (R17: -5%). Exactly 2 barriers/tile
// with counted vmcnt(4) is the local optimum at 2 waves/SIMD. Do not re-tune.
// MODE 1 epilogue: NON-TEMPORAL resid/out (f32x4 clang vec; R17: ~-6 us --
// the 268 MB single-use f32 streams stop evicting A/B panels from L2).
// MODE 0: write bf16 C.  MODE 1: out_f32 = resid + sigmoid(*scale)*C (N=2048,
// m-grouped XCD swizzle).
template<int MODE>
__global__ __launch_bounds__(512, 2)
void gemm_8ph(const u16* __restrict__ A, const u16* __restrict__ Bw,
              int M, int N, int K,
              u16* __restrict__ obf, const float* __restrict__ resid,
              float* __restrict__ of32, const float* __restrict__ scale_ptr) {
    __shared__ __align__(16) char lsb[2][65536];  // per buf: A-k0|A-k1|B-k0|B-k1 (16KB each)
    const int tid = threadIdx.x;
    const int lane = tid & 63;
    const int wm = (tid >> 6) >> 2;   // 0..1
    const int wn = (tid >> 6) & 3;    // 0..3
    const int r15 = lane & 15;
    const int nbx = N >> 8;

    int m0, n0;
    if (MODE == 1) {
        // m-grouped XCD swizzle (requires nbx == 8): XCD x -> m in [x*8, x*8+8)
        int x = blockIdx.x & 7, idx = blockIdx.x >> 3;
        int ml = idx >> 3, n = idx & 7;
        m0 = (x * 8 + ml) << 8;
        n0 = n << 8;
    } else {
        int bid = blockIdx.x;
        const int cpx = gridDim.x >> 3;
        bid = (bid & 7) * cpx + (bid >> 3);
        m0 = (bid / nbx) << 8;
        n0 = (bid % nbx) << 8;
    }

    f32x4 acc[8][4];
#pragma unroll
    for (int i = 0; i < 8; ++i)
#pragma unroll
        for (int j = 0; j < 4; ++j) acc[i][j] = (f32x4){0.f, 0.f, 0.f, 0.f};

    const char* Ab = (const char*)A;
    const char* Bb = (const char*)Bw;
    const int ssl = (((tid & 3) ^ ((tid >> 3) & 3)) << 4);        // staging src slot
    const int slotRd = ((((lane >> 4) ^ ((r15 >> 1) & 3))) << 4); // read slot
    const int nkt = K >> 6;

    // stage one 16KB half: matrix mat (0=A,1=B), k-half kh, of tile kt -> buf
    auto stage_half = [&](int buf, int mat, int kh, int kt) {
        const char* src = mat ? Bb : Ab;
        const int b0 = mat ? n0 : m0;
        char* dst = &lsb[buf][0] + mat * 32768 + kh * 16384;
        const int k0 = kt * 64 + kh * 32;
#pragma unroll
        for (int i = 0; i < 2; ++i) {
            int row = i * 128 + (tid >> 2);
            async16(src + ((size_t)(b0 + row) * K + k0) * 2 + ssl,
                    dst + i * 8192 + tid * 16);
        }
    };

    // prologue: tile 0, all 4 halves in canonical queue order
    stage_half(0, 0, 0, 0);
    stage_half(0, 1, 0, 0);
    stage_half(0, 0, 1, 0);
    stage_half(0, 1, 1, 0);

    for (int kt = 0; kt < nkt; ++kt) {
        const int cur = kt & 1;
        const char* base = &lsb[cur][0];
#pragma unroll
        for (int kh = 0; kh < 2; ++kh) {
            // ---- phase 2*kh: k-half publish + m-low quadrant ----
            if (kt < nkt - 1) asm volatile("s_waitcnt vmcnt(4)" ::: "memory");
            else if (kh == 0) asm volatile("s_waitcnt vmcnt(0)" ::: "memory");
            __builtin_amdgcn_s_barrier();
            if (kt + 1 < nkt) stage_half(cur ^ 1, 0, kh, kt + 1);   // A-kh of next

            const char* Ak = base + kh * 16384;
            const char* Bk = base + 32768 + kh * 16384;
            bf16x8 bf[4], afl[4];
#pragma unroll
            for (int n = 0; n < 4; ++n) {
                int row = wn * 64 + n * 16 + r15;
                bf[n] = *(const bf16x8*)(Bk + row * 64 + slotRd);
            }
#pragma unroll
            for (int m = 0; m < 4; ++m) {
                int row = wm * 128 + m * 16 + r15;
                afl[m] = *(const bf16x8*)(Ak + row * 64 + slotRd);
            }
            __builtin_amdgcn_s_setprio(1);
#pragma unroll
            for (int m = 0; m < 4; ++m)
#pragma unroll
                for (int n = 0; n < 4; ++n)
                    acc[m][n] = __builtin_amdgcn_mfma_f32_16x16x32_bf16(bf[n], afl[m], acc[m][n], 0, 0, 0);
            __builtin_amdgcn_s_setprio(0);

            // ---- phase 2*kh+1: m-high quadrant (no barrier needed) ----
            if (kt + 1 < nkt) stage_half(cur ^ 1, 1, kh, kt + 1);   // B-kh of next
            bf16x8 afh[4];
#pragma unroll
            for (int m = 0; m < 4; ++m) {
                int row = wm * 128 + 64 + m * 16 + r15;
                afh[m] = *(const bf16x8*)(Ak + row * 64 + slotRd);
            }
            __builtin_amdgcn_s_setprio(1);
#pragma unroll
            for (int m = 0; m < 4; ++m)
#pragma unroll
                for (int n = 0; n < 4; ++n)
                    acc[4 + m][n] = __builtin_amdgcn_mfma_f32_16x16x32_bf16(bf[n], afh[m], acc[4 + m][n], 0, 0, 0);
            __builtin_amdgcn_s_setprio(0);
        }
    }

    float sig = 0.f;
    if (MODE == 1) sig = 1.f / (1.f + expf(-scale_ptr[0]));

    // Swapped C/D layout: M-row = lane&15 (+m*16), N-col = (lane>>4)*4 + r (+n*16)
    const int crow = wm * 128 + r15;
    const int ccol0 = wn * 64 + ((lane >> 4) << 2);
#pragma unroll
    for (int m = 0; m < 8; ++m) {
#pragma unroll
        for (int n = 0; n < 4; ++n) {
            size_t gi = (size_t)(m0 + crow + m * 16) * N + (n0 + ccol0 + n * 16);
            if (MODE == 0) {
                ushort4 u;
                u.x = f2b(acc[m][n][0]); u.y = f2b(acc[m][n][1]);
                u.z = f2b(acc[m][n][2]); u.w = f2b(acc[m][n][3]);
                *(ushort4*)&obf[gi] = u;
            } else {
                f32x4 rv = __builtin_nontemporal_load((const f32x4*)&resid[gi]);
                f32x4 o = rv + sig * acc[m][n];
                __builtin_nontemporal_store(o, (f32x4*)&of32[gi]);
            }
        }
    }
}

// ---------------- fused phase-reads + softmax + merged (q from qkv, stride 3072) ----
__global__ __launch_bounds__(256)
void reads_kernel(const u16* __restrict__ qkv, const u16* __restrict__ wp,
                  u16* __restrict__ merged) {
    __shared__ __align__(16) u16 lsW[384 * 64];   // swizzled
    const int tid = threadIdx.x, lane = tid & 63, w = tid >> 6;
    const int bh = blockIdx.x, tc = blockIdx.y;
    const int b = bh >> 4, h = bh & 15;

    const char* src = (const char*)(wp + (size_t)bh * 24576);
#pragma unroll
    for (int it = 0; it < 12; ++it) {
        int x = (it * 256 + tid) << 4;            // dest byte in LDS (linear)
        int row = x >> 7;
        int wb = x & 127;
        *(uint4*)((char*)lsW + x) = *(const uint4*)(src + row * 128 + (wb ^ ((row & 7) << 4)));
    }
    __syncthreads();

    for (int tt = 0; tt < 4; ++tt) {
        const int t0 = tc * 256 + tt * 64 + w * 16;
        const size_t qoff = ((size_t)b * 4096 + t0 + (lane & 15)) * 3072 + h * 64 + ((lane >> 4) << 3);
        uint4 a0u = *(const uint4*)&qkv[qoff];
        uint4 a1u = *(const uint4*)&qkv[qoff + 32];

        float ss = 0.f;
        {
            unsigned a[8] = {a0u.x, a0u.y, a0u.z, a0u.w, a1u.x, a1u.y, a1u.z, a1u.w};
#pragma unroll
            for (int i = 0; i < 8; ++i) {
                union { unsigned u; float f; } lo, hi;
                lo.u = a[i] << 16; hi.u = a[i] & 0xFFFF0000u;
                ss += lo.f * lo.f + hi.f * hi.f;
            }
        }
        ss += __shfl_xor(ss, 16);
        ss += __shfl_xor(ss, 32);
        float sc = 1.0f / fmaxf(sqrtf(ss), 1e-12f);   // lane-local: this lane's t-row

        bf16x8 a0 = __builtin_bit_cast(bf16x8, a0u);
        bf16x8 a1 = __builtin_bit_cast(bf16x8, a1u);

        f32x4 acc[24];
#pragma unroll
        for (int i = 0; i < 24; ++i) acc[i] = (f32x4){0.f, 0.f, 0.f, 0.f};
#pragma unroll
        for (int kk = 0; kk < 2; ++kk) {
            bf16x8 a = kk ? a1 : a0;
            const int kb = kk * 64 + ((lane >> 4) << 4);
#pragma unroll
            for (int nf = 0; nf < 24; ++nf) {
                int row = nf * 16 + (lane & 15);
                bf16x8 bb = *(const bf16x8*)((const char*)lsW + row * 128 + (kb ^ ((row & 7) << 4)));
                acc[nf] = __builtin_amdgcn_mfma_f32_16x16x32_bf16(bb, a, acc[nf], 0, 0, 0);
            }
        }

        // scores -> softmax over 6 phases (scalar per lane; lane owns t-row = lane&15)
        float alpha[6];
#pragma unroll
        for (int p = 0; p < 6; ++p) {
            float x = 0.f;
#pragma unroll
            for (int fv = 0; fv < 4; ++fv) {
                f32x4 v = acc[p * 4 + fv];
#pragma unroll
                for (int r = 0; r < 4; ++r) x += v[r] * v[r];
            }
            x += __shfl_xor(x, 16);
            x += __shfl_xor(x, 32);
            alpha[p] = sqrtf(x) * sc * (5.0f / 8.0f);  // TEMP/sqrt(DV)
        }
        {
            float m = alpha[0];
#pragma unroll
            for (int p = 1; p < 6; ++p) m = fmaxf(m, alpha[p]);
            float s = 0.f;
#pragma unroll
            for (int p = 0; p < 6; ++p) { float e = expf(alpha[p] - m); s += e; alpha[p] = e; }
            float inv = 1.f / s;
#pragma unroll
            for (int p = 0; p < 6; ++p) alpha[p] *= inv;
        }
#pragma unroll
        for (int fv = 0; fv < 4; ++fv) {
            float o[4];
#pragma unroll
            for (int r = 0; r < 4; ++r) {
                float acc_o = 0.f;
#pragma unroll
                for (int p = 0; p < 6; ++p) acc_o += alpha[p] * acc[p * 4 + fv][r];
                o[r] = acc_o * sc;
            }
            size_t gi = ((size_t)b * 4096 + t0 + (lane & 15)) * 1024
                        + h * 64 + fv * 16 + ((lane >> 4) << 2);
            ushort4 u;
            u.x = f2b(o[0]); u.y = f2b(o[1]); u.z = f2b(o[2]); u.w = f2b(o[3]);
            *(ushort4*)&merged[gi] = u;
        }
    }
}

// ---------------- MFMA residual: part[sp][bh][v][d] = sum_t v[t,v]*kn[t,d] -----------
// (HW-verified R11: passed) Fused k-norm; per 32-t chunk: coalesced k/v reads
// -> octet shfl norm -> swizzled transpose-write -> K=32 MFMA.
__global__ __launch_bounds__(256)
void resid_mfma(const u16* __restrict__ qkv, float* __restrict__ part) {
    __shared__ __align__(16) u16 kT[64 * 32];
    __shared__ __align__(16) u16 vT[64 * 32];
    const int bh = blockIdx.x, sp = blockIdx.y;
    const int b = bh >> 4, h = bh & 15;
    const int tid = threadIdx.x, lane = tid & 63, wv = tid >> 6;
    const int tl = tid >> 3;   // 0..31: t within chunk
    const int c8 = tid & 7;    // d-octet

    f32x4 acc[4];
#pragma unroll
    for (int dt = 0; dt < 4; ++dt) acc[dt] = (f32x4){0.f, 0.f, 0.f, 0.f};

    const int r15 = lane & 15, g = lane >> 4;
    const int vrow = wv * 16 + r15;
    const int vaddr = vrow * 64 + ((g ^ ((vrow >> 3) & 3)) << 4);
    int kaddr[4];
#pragma unroll
    for (int dt = 0; dt < 4; ++dt) {
        int kr = dt * 16 + r15;
        kaddr[dt] = kr * 64 + ((g ^ ((kr >> 3) & 3)) << 4);
    }

    for (int c = 0; c < 8; ++c) {
        size_t row = ((size_t)b * 4096 + sp * 256 + c * 32 + tl) * 3072 + h * 64 + c8 * 8;
        uint4 kq = *(const uint4*)&qkv[row + 1024];
        uint4 vq = *(const uint4*)&qkv[row + 2048];

        unsigned kw[4] = {kq.x, kq.y, kq.z, kq.w};
        unsigned vw[4] = {vq.x, vq.y, vq.z, vq.w};
        float kf[8];
        float ss = 0.f;
#pragma unroll
        for (int i = 0; i < 4; ++i) {
            union { unsigned u; float f; } lo, hi;
            lo.u = kw[i] << 16; hi.u = kw[i] & 0xFFFF0000u;
            kf[2 * i] = lo.f; kf[2 * i + 1] = hi.f;
            ss += lo.f * lo.f + hi.f * hi.f;
        }
        ss += __shfl_xor(ss, 1);
        ss += __shfl_xor(ss, 2);
        ss += __shfl_xor(ss, 4);
        float sc = 1.0f / fmaxf(sqrtf(ss), 1e-12f);

        const int gt = (tl >> 3), o = (tl & 7);
#pragma unroll
        for (int j = 0; j < 8; ++j) {
            int r = 8 * c8 + j;
            int a = r * 32 + ((gt ^ ((r >> 3) & 3)) * 8 + o);
            kT[a] = f2b(kf[j] * sc);
            vT[a] = (u16)((vw[j >> 1] >> ((j & 1) * 16)) & 0xFFFFu);
        }
        __syncthreads();

        bf16x8 vf = *(const bf16x8*)((const char*)vT + vaddr);
#pragma unroll
        for (int dt = 0; dt < 4; ++dt) {
            bf16x8 knf = *(const bf16x8*)((const char*)kT + kaddr[dt]);
            acc[dt] = __builtin_amdgcn_mfma_f32_16x16x32_bf16(knf, vf, acc[dt], 0, 0, 0);
        }
        __syncthreads();
    }

    float* dst = part + ((size_t)sp * 64 + bh) * 4096 + (size_t)vrow * 64;
#pragma unroll
    for (int dt = 0; dt < 4; ++dt) {
        float4 f4;
        f4.x = acc[dt][0]; f4.y = acc[dt][1]; f4.z = acc[dt][2]; f4.w = acc[dt][3];
        *(float4*)(dst + dt * 16 + g * 4) = f4;
    }
}

// ---------------- W_new = 0.9*aged + sum(part)/T ----------------
__global__ __launch_bounds__(256)
void wnew_kernel(const float* __restrict__ W, const float* __restrict__ part,
                 float* __restrict__ outW) {
    int idx = blockIdx.x * 256 + threadIdx.x;   // 262144
    int d = idx & 63;
    float w = W[idx];
    float rot = (d < 32) ? -W[idx + 32] : W[idx - 32];
    float invf = expf(-(float)(d & 31) * (9.210340371976184f / 32.f));
    float aged = w * cosf(invf) + rot * sinf(invf);
    float r = 0.f;
#pragma unroll
    for (int s = 0; s < 16; ++s) r += part[(size_t)s * 262144 + idx];
    outW[idx] = 0.9f * aged + r * (1.0f / 4096.0f);
}

extern "C" void kernel_launch(void* const* d_in, const int* in_sizes, int n_in,
                              void* d_out, int out_size, void* d_ws, size_t ws_size,
                              hipStream_t stream) {
    const float* hidden = (const float*)d_in[0];
    const float* Wturn  = (const float*)d_in[1];
    const float* qw     = (const float*)d_in[2];
    const float* ow     = (const float*)d_in[3];
    const float* kw     = (const float*)d_in[4];
    const float* vw     = (const float*)d_in[5];
    const float* rs     = (const float*)d_in[6];
    float* out  = (float*)d_out;
    float* outW = out + 33554432;

    char* ws = (char*)d_ws;
    u16* hid_bf = (u16*)(ws + 0);             // 16384x2048 bf16 (67,108,864 B)
    u16* qkv    = (u16*)(ws + 67108864);      // 16384x3072 bf16 (100,663,296 B)
    u16* mrg    = (u16*)(ws + 167772160);     // 16384x1024 bf16 (33,554,432 B)
    u16* wcat   = (u16*)(ws + 201326592);     // 3072x2048 bf16 (12,582,912 B): q|k|v
    u16* ow_bf  = (u16*)(ws + 213909504);     // 2048x1024 bf16 (4,194,304 B) -- contiguous after wcat
    u16* wp     = (u16*)(ws + 218103808);     // 64x384x64 bf16 (3,145,728 B)
    float* part = (float*)(ws + 222298112);   // 16x262144 f32 (end ~239 MB)

    cvt_kernel<<<4096, 256, 0, stream>>>(hidden, hid_bf, 33554432 / 4);
    cvt4_kernel<<<8192, 256, 0, stream>>>(qw, kw, vw, ow, wcat);   // wcat|ow_bf contiguous
    wprep_kernel<<<6144, 256, 0, stream>>>(Wturn, wp);

    // fused q|k|v projection: (16384x2048) @ (3072x2048)^T -> qkv
    gemm_8ph<0><<<768, 512, 0, stream>>>(hid_bf, wcat, 16384, 3072, 2048, qkv, nullptr, nullptr, nullptr);

    reads_kernel<<<dim3(64, 16), 256, 0, stream>>>(qkv, wp, mrg);
    gemm_8ph<1><<<512, 512, 0, stream>>>(mrg, ow_bf, 16384, 2048, 1024, nullptr, hidden, out, rs);
    resid_mfma<<<dim3(64, 16), 256, 0, stream>>>(qkv, part);
    wnew_kernel<<<1024, 256, 0, stream>>>(Wturn, part, outW);
}

// Round 19
// 427.890 us; speedup vs baseline: 1.0111x; 1.0015x over previous
//
#include <hip/hip_runtime.h>
#include <math.h>

typedef unsigned short u16;
typedef __bf16 bf16x8 __attribute__((ext_vector_type(8)));
typedef float f32x4 __attribute__((ext_vector_type(4)));

typedef __attribute__((address_space(1))) const void gas_t;
typedef __attribute__((address_space(3))) void las_t;

__device__ __forceinline__ void async16(const void* g, void* l) {
    __builtin_amdgcn_global_load_lds((gas_t*)g, (las_t*)l, 16, 0, 0);
}

__device__ __forceinline__ float b2f(u16 u) {
    union { unsigned u; float f; } c; c.u = ((unsigned)u) << 16; return c.f;
}
__device__ __forceinline__ u16 f2b(float f) {
    union { float f; unsigned u; } c; c.f = f;
    unsigned x = c.u + 0x7FFFu + ((c.u >> 16) & 1u);
    return (u16)(x >> 16);
}

// ---------------- f32 -> bf16 conversion ----------------
__global__ __launch_bounds__(256)
void cvt_kernel(const float* __restrict__ in, u16* __restrict__ out, int n4) {
    int i = blockIdx.x * 256 + threadIdx.x;
    int stride = gridDim.x * 256;
    for (; i < n4; i += stride) {
        float4 f = ((const float4*)in)[i];
        ushort4 u;
        u.x = f2b(f.x); u.y = f2b(f.y); u.z = f2b(f.z); u.w = f2b(f.w);
        ((ushort4*)out)[i] = u;
    }
}

// ---------------- 4-source f32 -> bf16 into contiguous wcat|ow (q|k|v|o) -----------
__global__ __launch_bounds__(256)
void cvt4_kernel(const float* __restrict__ a, const float* __restrict__ b,
                 const float* __restrict__ c, const float* __restrict__ d,
                 u16* __restrict__ out) {
    int i = blockIdx.x * 256 + threadIdx.x;        // 0..2097151 quads
    int seg = i >> 19, off = i & 524287;           // 524288 quads per 2M-elem weight
    const float* src = (seg == 0) ? a : (seg == 1) ? b : (seg == 2) ? c : d;
    float4 f = ((const float4*)src)[off];
    ushort4 u;
    u.x = f2b(f.x); u.y = f2b(f.y); u.z = f2b(f.z); u.w = f2b(f.w);
    ((ushort4*)out)[i] = u;
}

// ---------------- rotated phase-weights: wp[bh][p*64+v][d] ----------------
// Fold RoPE into W (adjoint of rotate_half):
//   Wp[v,d] = cos_p[d]*W[v,d] + sin_p[d]*( d<32 ? +W[v,d+32] : -W[v,d-32] )
__global__ __launch_bounds__(256)
void wprep_kernel(const float* __restrict__ W, u16* __restrict__ wp) {
    int idx = blockIdx.x * 256 + threadIdx.x;   // < 64*6*64*64 = 1572864
    int d = idx & 63;
    int v = (idx >> 6) & 63;
    int p = (idx >> 12) % 6;
    int bh = idx / 24576;
    const float* Wb = W + (((size_t)bh * 64 + v) << 6);
    float invf = expf(-(float)(d & 31) * (9.210340371976184f / 32.f)); // 10000^(-(d%32)/32)
    float ang = (float)p * invf;
    float c = cosf(ang), s = sinf(ang);
    float rot = (d < 32) ? Wb[d + 32] : -Wb[d - 32];
    wp[idx] = f2b(c * Wb[d] + s * rot);
}

// ---------------- 256^2-tile bf16 GEMM, fine-grained 4-phase pipeline (R13-exact)
// C = A @ Bw^T. A: MxK, Bw: NxK, row-major bf16. 512 threads = 8 waves (2Mx4N).
// LDS 128 KiB = 2 buf x { A[k0|k1] , B[k0|k1] } x 256 rows x 32 elems (64B rows).
// Per K-tile: 4 phases along (k-half, m-half); each phase: {stage 2 loads of
// NEXT tile's half || 4-8 ds_read_b128 of THIS phase's frags || 16 MFMA}.
// Waits: P0/P2 vmcnt(4) (counted, partial); vmcnt(0) only at the last tile.
// HW-verified R13/R15/R18: 986 TF, MfmaUtil 44.3%, 0 conflicts, reproducible.
// SCHEDULE IS SETTLED -- A/B history: coarse ring (R12: +3%), 1-barrier/tile
// (R14: -6%), lockstep phase barriers (R17: -5%). Exactly 2 barriers/tile
// with counted vmcnt(4) is the local optimum at 2 waves/SIMD. Do not re-tune.
// MODE 1 epilogue: NON-TEMPORAL resid/out (f32x4 clang vec): single-use f32
// streams (268 MB) no-allocate so A/B panels stay L2-resident.
// MODE 0: write bf16 C.  MODE 1: out_f32 = resid + sigmoid(*scale)*C (N=2048,
// m-grouped XCD swizzle).
template<int MODE>
__global__ __launch_bounds__(512, 2)
void gemm_8ph(const u16* __restrict__ A, const u16* __restrict__ Bw,
              int M, int N, int K,
              u16* __restrict__ obf, const float* __restrict__ resid,
              float* __restrict__ of32, const float* __restrict__ scale_ptr) {
    __shared__ __align__(16) char lsb[2][65536];  // per buf: A-k0|A-k1|B-k0|B-k1 (16KB each)
    const int tid = threadIdx.x;
    const int lane = tid & 63;
    const int wm = (tid >> 6) >> 2;   // 0..1
    const int wn = (tid >> 6) & 3;    // 0..3
    const int r15 = lane & 15;
    const int nbx = N >> 8;

    int m0, n0;
    if (MODE == 1) {
        // m-grouped XCD swizzle (requires nbx == 8): XCD x -> m in [x*8, x*8+8)
        int x = blockIdx.x & 7, idx = blockIdx.x >> 3;
        int ml = idx >> 3, n = idx & 7;
        m0 = (x * 8 + ml) << 8;
        n0 = n << 8;
    } else {
        int bid = blockIdx.x;
        const int cpx = gridDim.x >> 3;
        bid = (bid & 7) * cpx + (bid >> 3);
        m0 = (bid / nbx) << 8;
        n0 = (bid % nbx) << 8;
    }

    f32x4 acc[8][4];
#pragma unroll
    for (int i = 0; i < 8; ++i)
#pragma unroll
        for (int j = 0; j < 4; ++j) acc[i][j] = (f32x4){0.f, 0.f, 0.f, 0.f};

    const char* Ab = (const char*)A;
    const char* Bb = (const char*)Bw;
    const int ssl = (((tid & 3) ^ ((tid >> 3) & 3)) << 4);        // staging src slot
    const int slotRd = ((((lane >> 4) ^ ((r15 >> 1) & 3))) << 4); // read slot
    const int nkt = K >> 6;

    // stage one 16KB half: matrix mat (0=A,1=B), k-half kh, of tile kt -> buf
    auto stage_half = [&](int buf, int mat, int kh, int kt) {
        const char* src = mat ? Bb : Ab;
        const int b0 = mat ? n0 : m0;
        char* dst = &lsb[buf][0] + mat * 32768 + kh * 16384;
        const int k0 = kt * 64 + kh * 32;
#pragma unroll
        for (int i = 0; i < 2; ++i) {
            int row = i * 128 + (tid >> 2);
            async16(src + ((size_t)(b0 + row) * K + k0) * 2 + ssl,
                    dst + i * 8192 + tid * 16);
        }
    };

    // prologue: tile 0, all 4 halves in canonical queue order
    stage_half(0, 0, 0, 0);
    stage_half(0, 1, 0, 0);
    stage_half(0, 0, 1, 0);
    stage_half(0, 1, 1, 0);

    for (int kt = 0; kt < nkt; ++kt) {
        const int cur = kt & 1;
        const char* base = &lsb[cur][0];
#pragma unroll
        for (int kh = 0; kh < 2; ++kh) {
            // ---- phase 2*kh: k-half publish + m-low quadrant ----
            if (kt < nkt - 1) asm volatile("s_waitcnt vmcnt(4)" ::: "memory");
            else if (kh == 0) asm volatile("s_waitcnt vmcnt(0)" ::: "memory");
            __builtin_amdgcn_s_barrier();
            if (kt + 1 < nkt) stage_half(cur ^ 1, 0, kh, kt + 1);   // A-kh of next

            const char* Ak = base + kh * 16384;
            const char* Bk = base + 32768 + kh * 16384;
            bf16x8 bf[4], afl[4];
#pragma unroll
            for (int n = 0; n < 4; ++n) {
                int row = wn * 64 + n * 16 + r15;
                bf[n] = *(const bf16x8*)(Bk + row * 64 + slotRd);
            }
#pragma unroll
            for (int m = 0; m < 4; ++m) {
                int row = wm * 128 + m * 16 + r15;
                afl[m] = *(const bf16x8*)(Ak + row * 64 + slotRd);
            }
            __builtin_amdgcn_s_setprio(1);
#pragma unroll
            for (int m = 0; m < 4; ++m)
#pragma unroll
                for (int n = 0; n < 4; ++n)
                    acc[m][n] = __builtin_amdgcn_mfma_f32_16x16x32_bf16(bf[n], afl[m], acc[m][n], 0, 0, 0);
            __builtin_amdgcn_s_setprio(0);

            // ---- phase 2*kh+1: m-high quadrant (no barrier needed) ----
            if (kt + 1 < nkt) stage_half(cur ^ 1, 1, kh, kt + 1);   // B-kh of next
            bf16x8 afh[4];
#pragma unroll
            for (int m = 0; m < 4; ++m) {
                int row = wm * 128 + 64 + m * 16 + r15;
                afh[m] = *(const bf16x8*)(Ak + row * 64 + slotRd);
            }
            __builtin_amdgcn_s_setprio(1);
#pragma unroll
            for (int m = 0; m < 4; ++m)
#pragma unroll
                for (int n = 0; n < 4; ++n)
                    acc[4 + m][n] = __builtin_amdgcn_mfma_f32_16x16x32_bf16(bf[n], afh[m], acc[4 + m][n], 0, 0, 0);
            __builtin_amdgcn_s_setprio(0);
        }
    }

    float sig = 0.f;
    if (MODE == 1) sig = 1.f / (1.f + expf(-scale_ptr[0]));

    // Swapped C/D layout: M-row = lane&15 (+m*16), N-col = (lane>>4)*4 + r (+n*16)
    const int crow = wm * 128 + r15;
    const int ccol0 = wn * 64 + ((lane >> 4) << 2);
#pragma unroll
    for (int m = 0; m < 8; ++m) {
#pragma unroll
        for (int n = 0; n < 4; ++n) {
            size_t gi = (size_t)(m0 + crow + m * 16) * N + (n0 + ccol0 + n * 16);
            if (MODE == 0) {
                ushort4 u;
                u.x = f2b(acc[m][n][0]); u.y = f2b(acc[m][n][1]);
                u.z = f2b(acc[m][n][2]); u.w = f2b(acc[m][n][3]);
                *(ushort4*)&obf[gi] = u;
            } else {
                f32x4 rv = __builtin_nontemporal_load((const f32x4*)&resid[gi]);
                f32x4 o = rv + sig * acc[m][n];
                __builtin_nontemporal_store(o, (f32x4*)&of32[gi]);
            }
        }
    }
}

// ---------------- fused phase-reads + softmax + merged (q from qkv, stride 3072) ----
__global__ __launch_bounds__(256)
void reads_kernel(const u16* __restrict__ qkv, const u16* __restrict__ wp,
                  u16* __restrict__ merged) {
    __shared__ __align__(16) u16 lsW[384 * 64];   // swizzled
    const int tid = threadIdx.x, lane = tid & 63, w = tid >> 6;
    const int bh = blockIdx.x, tc = blockIdx.y;
    const int b = bh >> 4, h = bh & 15;

    const char* src = (const char*)(wp + (size_t)bh * 24576);
#pragma unroll
    for (int it = 0; it < 12; ++it) {
        int x = (it * 256 + tid) << 4;            // dest byte in LDS (linear)
        int row = x >> 7;
        int wb = x & 127;
        *(uint4*)((char*)lsW + x) = *(const uint4*)(src + row * 128 + (wb ^ ((row & 7) << 4)));
    }
    __syncthreads();

    for (int tt = 0; tt < 4; ++tt) {
        const int t0 = tc * 256 + tt * 64 + w * 16;
        const size_t qoff = ((size_t)b * 4096 + t0 + (lane & 15)) * 3072 + h * 64 + ((lane >> 4) << 3);
        uint4 a0u = *(const uint4*)&qkv[qoff];
        uint4 a1u = *(const uint4*)&qkv[qoff + 32];

        float ss = 0.f;
        {
            unsigned a[8] = {a0u.x, a0u.y, a0u.z, a0u.w, a1u.x, a1u.y, a1u.z, a1u.w};
#pragma unroll
            for (int i = 0; i < 8; ++i) {
                union { unsigned u; float f; } lo, hi;
                lo.u = a[i] << 16; hi.u = a[i] & 0xFFFF0000u;
                ss += lo.f * lo.f + hi.f * hi.f;
            }
        }
        ss += __shfl_xor(ss, 16);
        ss += __shfl_xor(ss, 32);
        float sc = 1.0f / fmaxf(sqrtf(ss), 1e-12f);   // lane-local: this lane's t-row

        bf16x8 a0 = __builtin_bit_cast(bf16x8, a0u);
        bf16x8 a1 = __builtin_bit_cast(bf16x8, a1u);

        f32x4 acc[24];
#pragma unroll
        for (int i = 0; i < 24; ++i) acc[i] = (f32x4){0.f, 0.f, 0.f, 0.f};
#pragma unroll
        for (int kk = 0; kk < 2; ++kk) {
            bf16x8 a = kk ? a1 : a0;
            const int kb = kk * 64 + ((lane >> 4) << 4);
#pragma unroll
            for (int nf = 0; nf < 24; ++nf) {
                int row = nf * 16 + (lane & 15);
                bf16x8 bb = *(const bf16x8*)((const char*)lsW + row * 128 + (kb ^ ((row & 7) << 4)));
                acc[nf] = __builtin_amdgcn_mfma_f32_16x16x32_bf16(bb, a, acc[nf], 0, 0, 0);
            }
        }

        // scores -> softmax over 6 phases (scalar per lane; lane owns t-row = lane&15)
        float alpha[6];
#pragma unroll
        for (int p = 0; p < 6; ++p) {
            float x = 0.f;
#pragma unroll
            for (int fv = 0; fv < 4; ++fv) {
                f32x4 v = acc[p * 4 + fv];
#pragma unroll
                for (int r = 0; r < 4; ++r) x += v[r] * v[r];
            }
            x += __shfl_xor(x, 16);
            x += __shfl_xor(x, 32);
            alpha[p] = sqrtf(x) * sc * (5.0f / 8.0f);  // TEMP/sqrt(DV)
        }
        {
            float m = alpha[0];
#pragma unroll
            for (int p = 1; p < 6; ++p) m = fmaxf(m, alpha[p]);
            float s = 0.f;
#pragma unroll
            for (int p = 0; p < 6; ++p) { float e = expf(alpha[p] - m); s += e; alpha[p] = e; }
            float inv = 1.f / s;
#pragma unroll
            for (int p = 0; p < 6; ++p) alpha[p] *= inv;
        }
#pragma unroll
        for (int fv = 0; fv < 4; ++fv) {
            float o[4];
#pragma unroll
            for (int r = 0; r < 4; ++r) {
                float acc_o = 0.f;
#pragma unroll
                for (int p = 0; p < 6; ++p) acc_o += alpha[p] * acc[p * 4 + fv][r];
                o[r] = acc_o * sc;
            }
            size_t gi = ((size_t)b * 4096 + t0 + (lane & 15)) * 1024
                        + h * 64 + fv * 16 + ((lane >> 4) << 2);
            ushort4 u;
            u.x = f2b(o[0]); u.y = f2b(o[1]); u.z = f2b(o[2]); u.w = f2b(o[3]);
            *(ushort4*)&merged[gi] = u;
        }
    }
}

// ---------------- MFMA residual: part[sp][bh][v][d] = sum_t v[t,v]*kn[t,d] -----------
// (HW-verified R11: passed) Fused k-norm; per 32-t chunk: coalesced k/v reads
// -> octet shfl norm -> swizzled transpose-write -> K=32 MFMA.
__global__ __launch_bounds__(256)
void resid_mfma(const u16* __restrict__ qkv, float* __restrict__ part) {
    __shared__ __align__(16) u16 kT[64 * 32];
    __shared__ __align__(16) u16 vT[64 * 32];
    const int bh = blockIdx.x, sp = blockIdx.y;
    const int b = bh >> 4, h = bh & 15;
    const int tid = threadIdx.x, lane = tid & 63, wv = tid >> 6;
    const int tl = tid >> 3;   // 0..31: t within chunk
    const int c8 = tid & 7;    // d-octet

    f32x4 acc[4];
#pragma unroll
    for (int dt = 0; dt < 4; ++dt) acc[dt] = (f32x4){0.f, 0.f, 0.f, 0.f};

    const int r15 = lane & 15, g = lane >> 4;
    const int vrow = wv * 16 + r15;
    const int vaddr = vrow * 64 + ((g ^ ((vrow >> 3) & 3)) << 4);
    int kaddr[4];
#pragma unroll
    for (int dt = 0; dt < 4; ++dt) {
        int kr = dt * 16 + r15;
        kaddr[dt] = kr * 64 + ((g ^ ((kr >> 3) & 3)) << 4);
    }

    for (int c = 0; c < 8; ++c) {
        size_t row = ((size_t)b * 4096 + sp * 256 + c * 32 + tl) * 3072 + h * 64 + c8 * 8;
        uint4 kq = *(const uint4*)&qkv[row + 1024];
        uint4 vq = *(const uint4*)&qkv[row + 2048];

        unsigned kw[4] = {kq.x, kq.y, kq.z, kq.w};
        unsigned vw[4] = {vq.x, vq.y, vq.z, vq.w};
        float kf[8];
        float ss = 0.f;
#pragma unroll
        for (int i = 0; i < 4; ++i) {
            union { unsigned u; float f; } lo, hi;
            lo.u = kw[i] << 16; hi.u = kw[i] & 0xFFFF0000u;
            kf[2 * i] = lo.f; kf[2 * i + 1] = hi.f;
            ss += lo.f * lo.f + hi.f * hi.f;
        }
        ss += __shfl_xor(ss, 1);
        ss += __shfl_xor(ss, 2);
        ss += __shfl_xor(ss, 4);
        float sc = 1.0f / fmaxf(sqrtf(ss), 1e-12f);

        const int gt = (tl >> 3), o = (tl & 7);
#pragma unroll
        for (int j = 0; j < 8; ++j) {
            int r = 8 * c8 + j;
            int a = r * 32 + ((gt ^ ((r >> 3) & 3)) * 8 + o);
            kT[a] = f2b(kf[j] * sc);
            vT[a] = (u16)((vw[j >> 1] >> ((j & 1) * 16)) & 0xFFFFu);
        }
        __syncthreads();

        bf16x8 vf = *(const bf16x8*)((const char*)vT + vaddr);
#pragma unroll
        for (int dt = 0; dt < 4; ++dt) {
            bf16x8 knf = *(const bf16x8*)((const char*)kT + kaddr[dt]);
            acc[dt] = __builtin_amdgcn_mfma_f32_16x16x32_bf16(knf, vf, acc[dt], 0, 0, 0);
        }
        __syncthreads();
    }

    float* dst = part + ((size_t)sp * 64 + bh) * 4096 + (size_t)vrow * 64;
#pragma unroll
    for (int dt = 0; dt < 4; ++dt) {
        float4 f4;
        f4.x = acc[dt][0]; f4.y = acc[dt][1]; f4.z = acc[dt][2]; f4.w = acc[dt][3];
        *(float4*)(dst + dt * 16 + g * 4) = f4;
    }
}

// ---------------- W_new = 0.9*aged + sum(part)/T ----------------
__global__ __launch_bounds__(256)
void wnew_kernel(const float* __restrict__ W, const float* __restrict__ part,
                 float* __restrict__ outW) {
    int idx = blockIdx.x * 256 + threadIdx.x;   // 262144
    int d = idx & 63;
    float w = W[idx];
    float rot = (d < 32) ? -W[idx + 32] : W[idx - 32];
    float invf = expf(-(float)(d & 31) * (9.210340371976184f / 32.f));
    float aged = w * cosf(invf) + rot * sinf(invf);
    float r = 0.f;
#pragma unroll
    for (int s = 0; s < 16; ++s) r += part[(size_t)s * 262144 + idx];
    outW[idx] = 0.9f * aged + r * (1.0f / 4096.0f);
}

extern "C" void kernel_launch(void* const* d_in, const int* in_sizes, int n_in,
                              void* d_out, int out_size, void* d_ws, size_t ws_size,
                              hipStream_t stream) {
    const float* hidden = (const float*)d_in[0];
    const float* Wturn  = (const float*)d_in[1];
    const float* qw     = (const float*)d_in[2];
    const float* ow     = (const float*)d_in[3];
    const float* kw     = (const float*)d_in[4];
    const float* vw     = (const float*)d_in[5];
    const float* rs     = (const float*)d_in[6];
    float* out  = (float*)d_out;
    float* outW = out + 33554432;

    char* ws = (char*)d_ws;
    u16* hid_bf = (u16*)(ws + 0);             // 16384x2048 bf16 (67,108,864 B)
    u16* qkv    = (u16*)(ws + 67108864);      // 16384x3072 bf16 (100,663,296 B)
    u16* mrg    = (u16*)(ws + 167772160);     // 16384x1024 bf16 (33,554,432 B)
    u16* wcat   = (u16*)(ws + 201326592);     // 3072x2048 bf16 (12,582,912 B): q|k|v
    u16* ow_bf  = (u16*)(ws + 213909504);     // 2048x1024 bf16 (4,194,304 B) -- contiguous after wcat
    u16* wp     = (u16*)(ws + 218103808);     // 64x384x64 bf16 (3,145,728 B)
    float* part = (float*)(ws + 222298112);   // 16x262144 f32 (end ~239 MB)

    cvt_kernel<<<4096, 256, 0, stream>>>(hidden, hid_bf, 33554432 / 4);
    cvt4_kernel<<<8192, 256, 0, stream>>>(qw, kw, vw, ow, wcat);   // wcat|ow_bf contiguous
    wprep_kernel<<<6144, 256, 0, stream>>>(Wturn, wp);

    // fused q|k|v projection: (16384x2048) @ (3072x2048)^T -> qkv
    gemm_8ph<0><<<768, 512, 0, stream>>>(hid_bf, wcat, 16384, 3072, 2048, qkv, nullptr, nullptr, nullptr);

    reads_kernel<<<dim3(64, 16), 256, 0, stream>>>(qkv, wp, mrg);
    gemm_8ph<1><<<512, 512, 0, stream>>>(mrg, ow_bf, 16384, 2048, 1024, nullptr, hidden, out, rs);
    resid_mfma<<<dim3(64, 16), 256, 0, stream>>>(qkv, part);
    wnew_kernel<<<1024, 256, 0, stream>>>(Wturn, part, outW);
}